// Round 3
// baseline (67.838 us; speedup 1.0000x reference)
//
#include <hip/hip_runtime.h>
#include <cstdint>

// MMCL loss: per-row top-K hard negatives.
// M=4096 rows, N=13000 cols fp32; K = int(0.01*(N-1)) = 129.
// loss_row = 5*(1-pos)^2 + mean_{topK negatives}((1+v)^2); output = mean over rows.
//
// One 256-thread block per row. Streaming pass: each thread keeps values > t0
// in a PRIVATE LDS segment (16 slots, stride 17 -> own-segment scans are
// bank-conflict-free); no cross-lane ops in the hot loop. The positive column
// is NOT excluded during streaming; it is exactly removed later (uniform
// scalar corrections to the radix histograms and the final sum).
// An 8-pass 4-bit radix select over the ~300 candidates finds the exact K-th
// largest negative T; loss uses sum_{v>T}(1+v)^2 + (K-cnt)*(1+T)^2 (exact
// under ties, == lax.top_k sum). Pathological distributions fall back to
// threshold bisection in sortable-key space (never triggered for this data).

constexpr int M_ROWS = 4096;
constexpr int N_COLS = 13000;
constexpr int N4     = N_COLS / 4;    // 3250 float4s, 13000 % 4 == 0
constexpr int KSEL   = 129;           // int(0.01 * 12999)
constexpr int BLOCK  = 256;
constexpr int NWAVE  = BLOCK / 64;    // 4
constexpr int TCAP   = 16;            // per-thread candidate slots (mean ~1.2)
constexpr int SEGP   = TCAP + 1;      // padded stride (17 odd -> conflict-free)
constexpr float DELTA_C = 5.0f;
constexpr float T0   = 2.0f;

// monotone float -> uint32 key (larger float => larger key)
__device__ __forceinline__ uint32_t f2key(float f) {
    uint32_t u = __float_as_uint(f);
    return u ^ ((u & 0x80000000u) ? 0xFFFFFFFFu : 0x80000000u);
}
__device__ __forceinline__ float key2f(uint32_t k) {
    uint32_t u = (k & 0x80000000u) ? (k ^ 0x80000000u) : ~k;
    return __uint_as_float(u);
}

__global__ __launch_bounds__(BLOCK) void row_loss_kernel(
    const float* __restrict__ inputs,
    const int*   __restrict__ targets,
    float*       __restrict__ row_loss)
{
    __shared__ float cand[BLOCK * SEGP];   // thread-private segments
    __shared__ int   s_hist[16];
    __shared__ int   s_isum[NWAVE];
    __shared__ int   s_imax[NWAVE];
    __shared__ float s_fpart[NWAVE];
    __shared__ int   s_ipart[NWAVE];
    __shared__ int   s_bucket;
    __shared__ int   s_need;

    const int row  = blockIdx.x;
    const int tid  = threadIdx.x;
    const int wid  = tid >> 6;
    const int lane = tid & 63;
    const float* rp = inputs + (size_t)row * N_COLS;
    const int pos = targets[row];
    const float pos_v = rp[pos];           // uniform broadcast load

    float* seg = cand + tid * SEGP;

    // ---- candidate collection (common case: one pass at t = 2.0) ----
    uint32_t keyA = 0u;           // bracket: overflow side
    uint32_t keyB = 0xFFFFFFFFu;  // bracket: too-few side
    float t = T0;
    bool collapsed = false;       // K-th largest negative known exactly (Tval)
    float Tval = 0.0f;
    int cnt = 0;                  // true per-thread match count (may exceed TCAP)

    for (int iter = 0; iter < 64; ++iter) {
        cnt = 0;
        for (int j4 = tid; j4 < N4; j4 += BLOCK) {
            const float4 v = reinterpret_cast<const float4*>(rp)[j4];
            if (v.x > t) { if (cnt < TCAP) seg[cnt] = v.x; ++cnt; }
            if (v.y > t) { if (cnt < TCAP) seg[cnt] = v.y; ++cnt; }
            if (v.z > t) { if (cnt < TCAP) seg[cnt] = v.z; ++cnt; }
            if (v.w > t) { if (cnt < TCAP) seg[cnt] = v.w; ++cnt; }
        }
        // block-wide: total count and max per-thread count
        int ssum = cnt, smax = cnt;
        #pragma unroll
        for (int off = 32; off > 0; off >>= 1) {
            ssum += __shfl_down(ssum, off);
            smax = max(smax, __shfl_down(smax, off));
        }
        if (lane == 0) { s_isum[wid] = ssum; s_imax[wid] = smax; }
        __syncthreads();
        const int total = s_isum[0] + s_isum[1] + s_isum[2] + s_isum[3];
        const int mx    = max(max(s_imax[0], s_imax[1]), max(s_imax[2], s_imax[3]));
        __syncthreads();   // protect s_isum/s_imax before next-iteration reuse

        const int npos = (pos_v > t) ? 1 : 0;      // positive inside candidates?
        const bool ovf = mx > TCAP;
        if (collapsed || (!ovf && (total - npos) >= KSEL)) break;

        const uint32_t kt = f2key(t);
        if (ovf) keyA = kt; else keyB = kt;
        if (keyB - keyA <= 1u) {
            // no representable float strictly between brackets -> exact T
            Tval = key2f(keyB);
            t = Tval;
            collapsed = true;
            continue;
        }
        t = key2f(keyA + (keyB - keyA) / 2u);
    }

    const int mycnt = cnt < TCAP ? cnt : TCAP;
    const uint32_t key_pos = f2key(pos_v);
    const bool pos_in = (pos_v > t);   // positive present in candidate multiset

    // ---- exact K-th largest negative via 8-pass 4-bit radix select ----
    float T;
    if (collapsed) {
        T = Tval;
    } else {
        uint32_t hi = 0;   // chosen high bits (low bits zero)
        int need = KSEL;
        for (int shift = 28; shift >= 0; shift -= 4) {
            if (tid < 16) s_hist[tid] = 0;
            __syncthreads();
            const uint32_t maskHigh = (uint32_t)(0xFFFFFFFFull << (shift + 4));
            for (int j = 0; j < mycnt; ++j) {
                const uint32_t k = f2key(seg[j]);
                if ((k & maskHigh) == hi)
                    atomicAdd(&s_hist[(k >> shift) & 15], 1);
            }
            __syncthreads();
            if (tid == 0) {
                // remove the positive's contribution from this refinement level
                if (pos_in && ((key_pos & maskHigh) == hi))
                    s_hist[(key_pos >> shift) & 15] -= 1;
                int cum = 0, b = 15;
                for (; b > 0; --b) {
                    const int h = s_hist[b];
                    if (cum + h >= need) break;
                    cum += h;
                }
                s_bucket = b;
                s_need = need - cum;
            }
            __syncthreads();
            hi |= ((uint32_t)s_bucket) << shift;
            need = s_need;
        }
        T = key2f(hi);
    }

    // ---- sum f(v)=(1+v)^2 over v > T, pad with (K-cnt) copies of f(T) ----
    float s = 0.0f;
    int g = 0;
    for (int j = 0; j < mycnt; ++j) {
        const float x = seg[j];
        if (x > T) { const float u = 1.0f + x; s += u * u; ++g; }
    }
    #pragma unroll
    for (int off = 32; off > 0; off >>= 1) {
        s += __shfl_down(s, off);
        g += __shfl_down(g, off);
    }
    if (lane == 0) { s_fpart[wid] = s; s_ipart[wid] = g; }
    __syncthreads();
    if (tid == 0) {
        float ss = s_fpart[0] + s_fpart[1] + s_fpart[2] + s_fpart[3];
        int   gg = s_ipart[0] + s_ipart[1] + s_ipart[2] + s_ipart[3];
        if (pos_in && pos_v > T) {     // exact removal of the positive column
            const float u = 1.0f + pos_v;
            ss -= u * u;
            gg -= 1;
        }
        const float uT = 1.0f + T;
        const float neg = (ss + (float)(KSEL - gg) * uT * uT) / (float)KSEL;
        const float d = 1.0f - pos_v;
        row_loss[row] = DELTA_C * d * d + neg;
    }
}

__global__ __launch_bounds__(1024) void reduce_kernel(
    const float* __restrict__ row_loss, float* __restrict__ out)
{
    __shared__ float s[1024];
    float acc = 0.0f;
    for (int i = threadIdx.x; i < M_ROWS; i += 1024) acc += row_loss[i];
    s[threadIdx.x] = acc;
    __syncthreads();
    for (int off = 512; off > 0; off >>= 1) {
        if (threadIdx.x < off) s[threadIdx.x] += s[threadIdx.x + off];
        __syncthreads();
    }
    if (threadIdx.x == 0) out[0] = s[0] / (float)M_ROWS;
}

extern "C" void kernel_launch(void* const* d_in, const int* in_sizes, int n_in,
                              void* d_out, int out_size, void* d_ws, size_t ws_size,
                              hipStream_t stream) {
    const float* inputs  = (const float*)d_in[0];
    // d_in[1] = targets_ (unused by reference), d_in[3] = GT_MC (unused)
    const int*   targets = (const int*)d_in[2];
    float* row_loss = (float*)d_ws;   // 4096 floats = 16 KB scratch

    row_loss_kernel<<<M_ROWS, BLOCK, 0, stream>>>(inputs, targets, row_loss);
    reduce_kernel<<<1, 1024, 0, stream>>>(row_loss, (float*)d_out);
}

// Round 4
// 51.503 us; speedup vs baseline: 1.3172x; 1.3172x over previous
//
#include <hip/hip_runtime.h>
#include <cstdint>

// MMCL loss: per-row top-K hard negatives.
// M=4096 rows, N=13000 cols fp32; K = int(0.01*(N-1)) = 129.
// loss_row = 5*(1-pos)^2 + mean_{topK negatives}((1+v)^2); output = mean over rows.
//
// One 256-thread block per row. Streaming pass: 4x-unrolled, loads hoisted
// (4-12 float4 loads in flight per wave) to hide HBM/L2 latency; candidates
// (values > t0=2.0, expected ~296 for N(0,1)) compacted into per-wave LDS
// segments via ballot prefix (wave-uniform counter, no LDS atomics, no
// per-element column check). The positive column is included during streaming
// and exactly removed later via uniform scalar corrections (histogram + sum).
// An 8-pass 4-bit radix select over the candidates finds the exact K-th
// largest negative T; loss uses sum_{v>T}(1+v)^2 + (K-cnt)*(1+T)^2 (exact
// under ties, == lax.top_k). Pathological distributions fall back to exact
// threshold bisection in sortable-key space (never triggered for this data).

constexpr int M_ROWS = 4096;
constexpr int N_COLS = 13000;
constexpr int N4     = N_COLS / 4;        // 3250 float4s (13000 % 4 == 0)
constexpr int KSEL   = 129;               // int(0.01 * 12999)
constexpr int BLOCK  = 256;
constexpr int NWAVE  = BLOCK / 64;        // 4
constexpr int WCAP   = 320;               // per-wave candidate cap (~74 expected)
constexpr int FULL_IT  = N4 / (4 * BLOCK);        // 3 full unrolled strides
constexpr int TAIL_BASE = FULL_IT * 4 * BLOCK;    // 3072
constexpr int TAIL_N   = N4 - TAIL_BASE;          // 178 (< BLOCK)
constexpr float DELTA_C = 5.0f;
constexpr float T0   = 2.0f;

// monotone float -> uint32 key (larger float => larger key)
__device__ __forceinline__ uint32_t f2key(float f) {
    uint32_t u = __float_as_uint(f);
    return u ^ ((u & 0x80000000u) ? 0xFFFFFFFFu : 0x80000000u);
}
__device__ __forceinline__ float key2f(uint32_t k) {
    uint32_t u = (k & 0x80000000u) ? (k ^ 0x80000000u) : ~k;
    return __uint_as_float(u);
}

__global__ __launch_bounds__(BLOCK) void row_loss_kernel(
    const float* __restrict__ inputs,
    const int*   __restrict__ targets,
    float*       __restrict__ row_loss)
{
    __shared__ float cand[NWAVE * WCAP];   // per-wave segments
    __shared__ int   s_wcnt[NWAVE];
    __shared__ int   s_hist[16];
    __shared__ float s_fpart[NWAVE];
    __shared__ int   s_ipart[NWAVE];
    __shared__ int   s_bucket;
    __shared__ int   s_need;

    const int row  = blockIdx.x;
    const int tid  = threadIdx.x;
    const int wid  = tid >> 6;
    const int lane = tid & 63;
    const float* rp = inputs + (size_t)row * N_COLS;
    const float4* rp4 = reinterpret_cast<const float4*>(rp);
    const int pos = targets[row];
    const float pos_v = rp[pos];           // uniform broadcast load
    const uint64_t below = (1ull << lane) - 1ull;
    float* wseg = cand + wid * WCAP;

    // one full streaming pass at threshold t; returns wave-uniform match count
    auto stream_pass = [&](float t) -> int {
        int wcnt = 0;
        auto proc = [&](float x) {
            const uint64_t m = __ballot(x > t);
            if (m) {                                   // wave-uniform branch
                if (x > t) {
                    const int slot = wcnt + (int)__popcll(m & below);
                    if (slot < WCAP) wseg[slot] = x;
                }
                wcnt += (int)__popcll(m);              // uniform (scalar) add
            }
        };
        for (int it = 0; it < FULL_IT; ++it) {         // 3 iters, unrollable
            const int b = it * 4 * BLOCK + tid;
            const float4 v0 = rp4[b];
            const float4 v1 = rp4[b +     BLOCK];
            const float4 v2 = rp4[b + 2 * BLOCK];
            const float4 v3 = rp4[b + 3 * BLOCK];
            proc(v0.x); proc(v0.y); proc(v0.z); proc(v0.w);
            proc(v1.x); proc(v1.y); proc(v1.z); proc(v1.w);
            proc(v2.x); proc(v2.y); proc(v2.z); proc(v2.w);
            proc(v3.x); proc(v3.y); proc(v3.z); proc(v3.w);
        }
        // branchless tail: sentinel keeps ballot wave-uniform, never matches
        const float4 vt = (tid < TAIL_N) ? rp4[TAIL_BASE + tid]
                                         : make_float4(-1e30f, -1e30f, -1e30f, -1e30f);
        proc(vt.x); proc(vt.y); proc(vt.z); proc(vt.w);
        return wcnt;
    };

    // ---- candidate collection (common case: one pass at t = 2.0) ----
    uint32_t keyA = 0u;           // bracket: overflow side
    uint32_t keyB = 0xFFFFFFFFu;  // bracket: too-few side
    float t = T0;
    bool collapsed = false;       // K-th largest negative known exactly (Tval)
    float Tval = 0.0f;
    int cnt = 0;                  // this wave's candidate count (uniform)

    for (int iter = 0; iter < 64; ++iter) {
        cnt = stream_pass(t);
        if (lane == 0) s_wcnt[wid] = cnt;
        __syncthreads();
        const int c0 = s_wcnt[0], c1 = s_wcnt[1], c2 = s_wcnt[2], c3 = s_wcnt[3];
        __syncthreads();
        const int total = c0 + c1 + c2 + c3;
        const bool ovf = (c0 > WCAP) | (c1 > WCAP) | (c2 > WCAP) | (c3 > WCAP);
        const int npos = (pos_v > t) ? 1 : 0;   // positive inside candidates?

        if (collapsed || (!ovf && (total - npos) >= KSEL)) break;

        const uint32_t kt = f2key(t);
        if (ovf) keyA = kt; else keyB = kt;
        if (keyB - keyA <= 1u) {
            // no representable float strictly between brackets -> exact T
            Tval = key2f(keyB);
            t = Tval;
            collapsed = true;
            continue;
        }
        t = key2f(keyA + (keyB - keyA) / 2u);
    }

    const int mycnt = cnt < WCAP ? cnt : WCAP;     // wave-uniform
    const uint32_t key_pos = f2key(pos_v);
    const bool pos_in = (pos_v > t);   // positive present in candidate multiset

    // ---- exact K-th largest negative via 8-pass 4-bit radix select ----
    float T;
    if (collapsed) {
        T = Tval;   // candidates are exactly {v > T}, negative count < K
    } else {
        uint32_t hi = 0;   // chosen high bits (low bits zero)
        int need = KSEL;
        for (int shift = 28; shift >= 0; shift -= 4) {
            if (tid < 16) s_hist[tid] = 0;
            __syncthreads();
            const uint32_t maskHigh = (uint32_t)(0xFFFFFFFFull << (shift + 4));
            for (int c = lane; c < mycnt; c += 64) {   // wave scans own segment
                const uint32_t k = f2key(wseg[c]);
                if ((k & maskHigh) == hi)
                    atomicAdd(&s_hist[(k >> shift) & 15], 1);
            }
            __syncthreads();
            if (tid == 0) {
                // remove the positive column's contribution at this level
                if (pos_in && ((key_pos & maskHigh) == hi))
                    s_hist[(key_pos >> shift) & 15] -= 1;
                int cum = 0, b = 15;
                for (; b > 0; --b) {
                    const int h = s_hist[b];
                    if (cum + h >= need) break;
                    cum += h;
                }
                s_bucket = b;
                s_need = need - cum;
            }
            __syncthreads();
            hi |= ((uint32_t)s_bucket) << shift;
            need = s_need;
        }
        T = key2f(hi);
    }

    // ---- sum f(v)=(1+v)^2 over v > T, pad with (K-cnt) copies of f(T) ----
    float s = 0.0f;
    int g = 0;
    for (int c = lane; c < mycnt; c += 64) {
        const float x = wseg[c];
        if (x > T) { const float u = 1.0f + x; s += u * u; ++g; }
    }
    #pragma unroll
    for (int off = 32; off > 0; off >>= 1) {
        s += __shfl_down(s, off);
        g += __shfl_down(g, off);
    }
    if (lane == 0) { s_fpart[wid] = s; s_ipart[wid] = g; }
    __syncthreads();
    if (tid == 0) {
        float ss = s_fpart[0] + s_fpart[1] + s_fpart[2] + s_fpart[3];
        int   gg = s_ipart[0] + s_ipart[1] + s_ipart[2] + s_ipart[3];
        if (pos_in && pos_v > T) {     // exact removal of the positive column
            const float u = 1.0f + pos_v;
            ss -= u * u;
            gg -= 1;
        }
        const float uT = 1.0f + T;
        const float neg = (ss + (float)(KSEL - gg) * uT * uT) / (float)KSEL;
        const float d = 1.0f - pos_v;
        row_loss[row] = DELTA_C * d * d + neg;
    }
}

__global__ __launch_bounds__(1024) void reduce_kernel(
    const float* __restrict__ row_loss, float* __restrict__ out)
{
    __shared__ float s[1024];
    float acc = 0.0f;
    for (int i = threadIdx.x; i < M_ROWS; i += 1024) acc += row_loss[i];
    s[threadIdx.x] = acc;
    __syncthreads();
    for (int off = 512; off > 0; off >>= 1) {
        if (threadIdx.x < off) s[threadIdx.x] += s[threadIdx.x + off];
        __syncthreads();
    }
    if (threadIdx.x == 0) out[0] = s[0] / (float)M_ROWS;
}

extern "C" void kernel_launch(void* const* d_in, const int* in_sizes, int n_in,
                              void* d_out, int out_size, void* d_ws, size_t ws_size,
                              hipStream_t stream) {
    const float* inputs  = (const float*)d_in[0];
    // d_in[1] = targets_ (unused by reference), d_in[3] = GT_MC (unused)
    const int*   targets = (const int*)d_in[2];
    float* row_loss = (float*)d_ws;   // 4096 floats = 16 KB scratch

    row_loss_kernel<<<M_ROWS, BLOCK, 0, stream>>>(inputs, targets, row_loss);
    reduce_kernel<<<1, 1024, 0, stream>>>(row_loss, (float*)d_out);
}